// Round 3
// baseline (468.780 us; speedup 1.0000x reference)
//
#include <hip/hip_runtime.h>
#include <hip/hip_bf16.h>
#include <stdint.h>

#define T_ 2048
#define H_ 1024
#define I_ 2048
#define E_ 8
#define NE_ 9            // 8 routed + 1 shared (virtual expert)

typedef __attribute__((ext_vector_type(8))) short bf16x8;
typedef __attribute__((ext_vector_type(4))) float f32x4;

__device__ __forceinline__ unsigned short f2bf(float f) {
  unsigned int u; __builtin_memcpy(&u, &f, 4);
  u = (u + 0x7fffu + ((u >> 16) & 1u)) >> 16;
  return (unsigned short)u;
}
__device__ __forceinline__ void cvt2(float a, float b, unsigned short* dst) {
  __hip_bfloat162 h = __float22bfloat162_rn(float2{a, b});
  __builtin_memcpy(dst, &h, 4);
}
// async global->LDS DMA, 16B per lane; LDS dest = wave-uniform base + lane*16
__device__ __forceinline__ void gll16(const void* g, void* l) {
  __builtin_amdgcn_global_load_lds((const __attribute__((address_space(1))) void*)g,
                                   (__attribute__((address_space(3))) void*)l, 16, 0, 0);
}

// ---------------- pack weights: fp32 [K][N] -> bf16 blocked [nt64][kt32][q][nn][8] ----------------
// float4 coalesced loads + LDS transpose (stride 68 -> conflict-free column reads)
__global__ __launch_bounds__(256) void k_pack(
    const float* __restrict__ eg, const float* __restrict__ eu, const float* __restrict__ ed,
    const float* __restrict__ sg, const float* __restrict__ su, const float* __restrict__ sd,
    unsigned short* __restrict__ wgp, unsigned short* __restrict__ wup,
    unsigned short* __restrict__ wdp) {
  int kt = blockIdx.x, nt = blockIdx.y, z = blockIdx.z;
  int grp = z / NE_, e = z % NE_;
  int K = (grp == 2) ? I_ : H_;
  int N = (grp == 2) ? H_ : I_;
  if (kt * 32 >= K || nt * 64 >= N) return;
  const float* src; unsigned short* dst;
  if (grp == 0)      { src = (e < E_) ? eg + (size_t)e * H_ * I_ : sg; dst = wgp + (size_t)e * H_ * I_; }
  else if (grp == 1) { src = (e < E_) ? eu + (size_t)e * H_ * I_ : su; dst = wup + (size_t)e * H_ * I_; }
  else               { src = (e < E_) ? ed + (size_t)e * I_ * H_ : sd; dst = wdp + (size_t)e * I_ * H_; }

  __shared__ __align__(16) float lds[32 * 68];
  int t = threadIdx.x;
  const float* srcbase = src + (size_t)(kt * 32) * N + nt * 64;
  int r0 = t >> 4, c0 = (t & 15) * 4;
  float4 v0 = *(const float4*)(srcbase + (size_t)r0 * N + c0);
  float4 v1 = *(const float4*)(srcbase + (size_t)(r0 + 16) * N + c0);
  *(float4*)&lds[r0 * 68 + c0] = v0;
  *(float4*)&lds[(r0 + 16) * 68 + c0] = v1;
  __syncthreads();

  int q = t >> 6, nn = t & 63;
  unsigned short o[8];
#pragma unroll
  for (int j = 0; j < 8; j += 2) {
    float a = lds[(q * 8 + j) * 68 + nn];
    float b = lds[(q * 8 + j + 1) * 68 + nn];
    cvt2(a, b, &o[j]);
  }
  size_t tile = ((size_t)nt * (K / 32) + kt) * 2048;
  *(bf16x8*)&dst[tile + q * 512 + nn * 8] = *(bf16x8*)o;
}

// ---------------- router: 1 wave per token; NO global atomics ----------------
__global__ __launch_bounds__(256) void k_router(
    const float* __restrict__ x, const float* __restrict__ rw,
    int* __restrict__ topi, float* __restrict__ topw,
    float* __restrict__ probs, float* __restrict__ lse2) {
  __shared__ float lrw[E_ * H_];  // transposed [e][h], 32 KB
  int tid = threadIdx.x;
#pragma unroll
  for (int i = 0; i < 8; i++) {
    int idx = i * 256 + tid;          // float4 index over 2048
    float4 v = ((const float4*)rw)[idx];
    int f = idx * 4; int h = f >> 3; int e0 = f & 7;   // e0 in {0,4}
    lrw[(e0 + 0) * H_ + h] = v.x;
    lrw[(e0 + 1) * H_ + h] = v.y;
    lrw[(e0 + 2) * H_ + h] = v.z;
    lrw[(e0 + 3) * H_ + h] = v.w;
  }
  __syncthreads();
  int w = tid >> 6, lane = tid & 63;
  int t = blockIdx.x * 4 + w;
  const float* xp = x + (size_t)t * H_ + lane;
  float xr[16];
#pragma unroll
  for (int j = 0; j < 16; j++) xr[j] = xp[j * 64];   // coalesced dword loads
  float acc[E_];
#pragma unroll
  for (int e = 0; e < E_; e++) acc[e] = 0.f;
#pragma unroll
  for (int j = 0; j < 16; j++) {
    float xf = xr[j];
    const float* wp = &lrw[j * 64 + lane];           // lane-stride 1 -> conflict-free
#pragma unroll
    for (int e = 0; e < E_; e++) acc[e] += xf * wp[e * H_];
  }
#pragma unroll
  for (int off = 32; off >= 1; off >>= 1) {
#pragma unroll
    for (int e = 0; e < E_; e++) acc[e] += __shfl_xor(acc[e], off, 64);
  }
  if (lane == 0) {
    float m = acc[0];
#pragma unroll
    for (int e = 1; e < E_; e++) m = fmaxf(m, acc[e]);
    float p[E_], s = 0.f;
#pragma unroll
    for (int e = 0; e < E_; e++) { p[e] = expf(acc[e] - m); s += p[e]; }
    float inv = 1.f / s;
#pragma unroll
    for (int e = 0; e < E_; e++) p[e] *= inv;
    float lse = m + logf(s);
    lse2[t] = lse * lse;
    float4 p0 = {p[0], p[1], p[2], p[3]}, p1 = {p[4], p[5], p[6], p[7]};
    ((float4*)(probs + t * 8))[0] = p0;
    ((float4*)(probs + t * 8))[1] = p1;
    int i0 = 0;
#pragma unroll
    for (int e = 1; e < E_; e++) if (p[e] > p[i0]) i0 = e;
    int i1 = (i0 == 0) ? 1 : 0;
#pragma unroll
    for (int e = 0; e < E_; e++) if (e != i0 && e != i1 && p[e] > p[i1]) i1 = e;
    float w0 = p[i0], w1 = p[i1], wsum = w0 + w1;
    topi[t * 2] = i0; topi[t * 2 + 1] = i1;
    topw[t * 2] = w0 / wsum; topw[t * 2 + 1] = w1 / wsum;
  }
}

// ---------------- reduce: probs/lse2/counts -> cnt, poffs, aux ----------------
__global__ __launch_bounds__(256) void k_reduce(
    const float* __restrict__ probs, const float* __restrict__ lse2,
    const int* __restrict__ topi,
    int* cnt, int* poffs, float* out_aux) {
  __shared__ float sp[256][9];
  __shared__ int sc[256][8];
  int tid = threadIdx.x;
  float ps[9] = {0.f, 0.f, 0.f, 0.f, 0.f, 0.f, 0.f, 0.f, 0.f};
  int c[8] = {0, 0, 0, 0, 0, 0, 0, 0};
  for (int t = tid; t < T_; t += 256) {
#pragma unroll
    for (int e = 0; e < E_; e++) ps[e] += probs[t * 8 + e];
    ps[8] += lse2[t];
    c[topi[t * 2]]++; c[topi[t * 2 + 1]]++;
  }
#pragma unroll
  for (int e = 0; e < 9; e++) sp[tid][e] = ps[e];
#pragma unroll
  for (int e = 0; e < 8; e++) sc[tid][e] = c[e];
  __syncthreads();
  for (int s = 128; s > 0; s >>= 1) {
    if (tid < s) {
#pragma unroll
      for (int e = 0; e < 9; e++) sp[tid][e] += sp[tid + s][e];
#pragma unroll
      for (int e = 0; e < 8; e++) sc[tid][e] += sc[tid + s][e];
    }
    __syncthreads();
  }
  if (tid == 0) {
#pragma unroll
    for (int e = 0; e < E_; e++) cnt[e] = sc[0][e];
    cnt[E_] = T_;
    int po = 0;
    for (int e = 0; e < NE_; e++) { poffs[e] = po; po += ((cnt[e] + 127) >> 7) << 7; }
    poffs[NE_] = po;
    float lb = 0.f;
#pragma unroll
    for (int e = 0; e < E_; e++)
      lb += ((float)cnt[e] / 4096.f) * (sp[0][e] / 2048.f);
    out_aux[0] = 0.01f * 8.f * lb + 0.001f * (sp[0][8] / 2048.f);
  }
}

// ---------------- fill: LDS histogram, 8 global atomics per block ----------------
__global__ __launch_bounds__(256) void k_fill(
    const int* __restrict__ topi, const float* __restrict__ topw,
    const int* __restrict__ poffs, int* cur, int* tok, float* wgt) {
  __shared__ int hist[8];
  __shared__ int base[8];
  int tid = threadIdx.x;
  int t = blockIdx.x * 256 + tid;
  if (tid < 8) hist[tid] = 0;
  __syncthreads();
  int e0 = topi[t * 2], e1 = topi[t * 2 + 1];
  int p0 = atomicAdd(&hist[e0], 1);
  int p1 = atomicAdd(&hist[e1], 1);
  __syncthreads();
  if (tid < 8) base[tid] = atomicAdd(&cur[tid], hist[tid]);
  __syncthreads();
  tok[poffs[e0] + base[e0] + p0] = t; wgt[poffs[e0] + base[e0] + p0] = topw[t * 2];
  tok[poffs[e1] + base[e1] + p1] = t; wgt[poffs[e1] + base[e1] + p1] = topw[t * 2 + 1];
  int p8 = poffs[E_];
  tok[p8 + t] = t;
  wgt[p8 + t] = 1.f;
}

// ---------------- packA: gather x rows -> bf16 blocked A [rt][kt][q][m][8] ----------------
__global__ __launch_bounds__(256) void k_packA(
    const float* __restrict__ x, const int* __restrict__ cnt,
    const int* __restrict__ poffs, const int* __restrict__ tok,
    unsigned short* __restrict__ apack) {
  int kc = blockIdx.x, mt = blockIdx.y, e = blockIdx.z;
  int cnt_e = cnt[e];
  if (mt * 128 >= cnt_e) return;
  int po = poffs[e];
  int rt = (po >> 7) + mt;
  int t = threadIdx.x;
  int m = t & 127, qh = t >> 7;
  int atok = tok[po + min(mt * 128 + m, cnt_e - 1)];
  const float* arow = x + (size_t)atok * H_;
  size_t abase = (size_t)rt * 32 * 4096;
#pragma unroll
  for (int ki = 0; ki < 4; ki++) {
    int kt = kc * 4 + ki;
#pragma unroll
    for (int qo = 0; qo < 2; qo++) {
      int q = qh + qo * 2;
      const float* s = arow + kt * 32 + q * 8;
      float4 v0 = *(const float4*)s, v1 = *(const float4*)(s + 4);
      unsigned short t8[8];
      cvt2(v0.x, v0.y, t8); cvt2(v0.z, v0.w, t8 + 2);
      cvt2(v1.x, v1.y, t8 + 4); cvt2(v1.z, v1.w, t8 + 6);
      *(bf16x8*)&apack[abase + (size_t)kt * 4096 + q * 1024 + m * 8] = *(bf16x8*)t8;
    }
  }
}

// ---------------- GEMM1: h = silu(x*Wg)*(x*Wu) ----------------
// 1-D compacted grid over (rt, nt), XCD-swizzled (nt fastest within chunk so
// blocks sharing an A-tile share an XCD L2), double-buffered LDS prefetch
// (stage kt+1 while computing kt; ONE barrier per K-step).
#define G1_GRID 1792   // 56 rt-slots * 32 nt, multiple of 8
__global__ __launch_bounds__(256) void k_gemm1(
    const unsigned short* __restrict__ apack,
    const unsigned short* __restrict__ wgp, const unsigned short* __restrict__ wup,
    const int* __restrict__ cnt, const int* __restrict__ poffs,
    unsigned short* __restrict__ hbuf) {
  int lin = blockIdx.x;
  int s = (lin & 7) * (G1_GRID / 8) + (lin >> 3);   // bijective XCD chunk swizzle
  int rt = s >> 5, nt = s & 31;
  int rtTotal = poffs[NE_] >> 7;
  if (rt >= rtTotal) return;
  int ro = rt << 7;
  int e = 0;
#pragma unroll
  for (int i = 1; i < NE_; i++) if (poffs[i] <= ro) e = i;
  int po = poffs[e];
  int cnt_e = cnt[e];
  int mt = (ro - po) >> 7;

  __shared__ __align__(16) unsigned short As[2][4096];   // [q][m][8]
  __shared__ __align__(16) unsigned short BgS[2][2048];  // [q][nn][8]
  __shared__ __align__(16) unsigned short BuS[2][2048];

  int tid = threadIdx.x;
  int lane = tid & 63, w = tid >> 6;
  int quad = lane >> 4, l15 = lane & 15;
  int wm = w >> 1, wn = w & 1;

  const unsigned short* abase = apack + (size_t)rt * 32 * 4096;
  const unsigned short* bgb = wgp + (size_t)e * H_ * I_ + (size_t)nt * 32 * 2048;
  const unsigned short* bub = wup + (size_t)e * H_ * I_ + (size_t)nt * 32 * 2048;

  f32x4 zero = {0.f, 0.f, 0.f, 0.f};
  f32x4 accg[4][2], accu[4][2];
#pragma unroll
  for (int mi = 0; mi < 4; mi++)
#pragma unroll
    for (int ni = 0; ni < 2; ni++) { accg[mi][ni] = zero; accu[mi][ni] = zero; }

#define STAGE1(kt, b) do { \
    const unsigned short* asrc = abase + (size_t)(kt) * 4096 + w * 1024 + lane * 8; \
    gll16(asrc, &As[b][w * 1024]); \
    gll16(asrc + 512, &As[b][w * 1024 + 512]); \
    gll16(bgb + (size_t)(kt) * 2048 + w * 512 + lane * 8, &BgS[b][w * 512]); \
    gll16(bub + (size_t)(kt) * 2048 + w * 512 + lane * 8, &BuS[b][w * 512]); \
  } while (0)

  STAGE1(0, 0);
  __syncthreads();   // drains vmcnt(0): buf0 ready
  for (int kt = 0; kt < 32; kt++) {
    int cur = kt & 1;
    if (kt < 31) STAGE1(kt + 1, cur ^ 1);   // in flight under the compute below
    bf16x8 af[4];
#pragma unroll
    for (int mi = 0; mi < 4; mi++)
      af[mi] = *(const bf16x8*)&As[cur][quad * 1024 + (wm * 64 + mi * 16 + l15) * 8];
#pragma unroll
    for (int ni = 0; ni < 2; ni++) {
      bf16x8 bg = *(const bf16x8*)&BgS[cur][quad * 512 + (wn * 32 + ni * 16 + l15) * 8];
      bf16x8 bu = *(const bf16x8*)&BuS[cur][quad * 512 + (wn * 32 + ni * 16 + l15) * 8];
#pragma unroll
      for (int mi = 0; mi < 4; mi++) {
        accg[mi][ni] = __builtin_amdgcn_mfma_f32_16x16x32_bf16(af[mi], bg, accg[mi][ni], 0, 0, 0);
        accu[mi][ni] = __builtin_amdgcn_mfma_f32_16x16x32_bf16(af[mi], bu, accu[mi][ni], 0, 0, 0);
      }
    }
    __syncthreads();   // next buffer staged + everyone done reading cur
  }
#undef STAGE1

  // epilogue: silu(g)*u -> hbuf in gemm2's packed-A layout [rt][kt2][q2][m][8]
  size_t hbase = (size_t)rt * 64 * 4096;
  int rem = cnt_e - mt * 128;
#pragma unroll
  for (int ni = 0; ni < 2; ni++) {
    int cc = nt * 64 + wn * 32 + ni * 16 + l15;
    size_t cb = hbase + (size_t)(cc >> 5) * 4096 + (size_t)((cc >> 3) & 3) * 1024 + (cc & 7);
#pragma unroll
    for (int mi = 0; mi < 4; mi++)
#pragma unroll
      for (int r = 0; r < 4; r++) {
        int row = wm * 64 + mi * 16 + quad * 4 + r;
        if (row < rem) {
          float g = accg[mi][ni][r], u = accu[mi][ni][r];
          float sv = g / (1.f + __expf(-g));
          hbuf[cb + (size_t)row * 8] = f2bf(sv * u);
        }
      }
  }
}

// ---------------- GEMM2: out += w * (h * Wd); K-split x4, dbuf, swizzled ----------------
// 1792 blocks = 7/CU (LDS allows 5 resident) -> residency-saturating; the
// extra kh splits only add atomic-epilogue traffic (A/B reads stay disjoint).
#define G2_GRID 1792   // 56 rt-slots * 8 nt * 4 khalf, multiple of 8
__global__ __launch_bounds__(256) void k_gemm2(
    const unsigned short* __restrict__ hbuf, const unsigned short* __restrict__ wdp,
    const int* __restrict__ cnt, const int* __restrict__ poffs,
    const int* __restrict__ tok, const float* __restrict__ wgt,
    float* __restrict__ out) {
  int lin = blockIdx.x;
  int s = (lin & 7) * (G2_GRID / 8) + (lin >> 3);   // bijective XCD chunk swizzle
  int rt = s >> 5;                                  // chunk of 224 = 7 full rt groups
  int r5 = s & 31;
  int nt = r5 >> 2, kh = r5 & 3;
  int rtTotal = poffs[NE_] >> 7;
  if (rt >= rtTotal) return;
  int ro = rt << 7;
  int e = 0;
#pragma unroll
  for (int i = 1; i < NE_; i++) if (poffs[i] <= ro) e = i;
  int po = poffs[e];
  int cnt_e = cnt[e];
  int mt = (ro - po) >> 7;

  __shared__ __align__(16) unsigned short As[2][4096];   // [q][m][8]
  __shared__ __align__(16) unsigned short BdS[2][4096];  // [h][q][nn][8]

  int tid = threadIdx.x;
  int lane = tid & 63, w = tid >> 6;
  int quad = lane >> 4, l15 = lane & 15;
  int wm = w >> 1, wn = w & 1;

  const unsigned short* abase = hbuf + (size_t)rt * 64 * 4096;
  const unsigned short* bb0 = wdp + (size_t)e * I_ * H_ + ((size_t)(2 * nt) * 64) * 2048;
  const unsigned short* bb1 = wdp + (size_t)e * I_ * H_ + ((size_t)(2 * nt + 1) * 64) * 2048;

  f32x4 zero = {0.f, 0.f, 0.f, 0.f};
  f32x4 acc[4][4];
#pragma unroll
  for (int mi = 0; mi < 4; mi++)
#pragma unroll
    for (int ni = 0; ni < 4; ni++) acc[mi][ni] = zero;

#define STAGE2(kt, b) do { \
    const unsigned short* asrc = abase + (size_t)(kt) * 4096 + w * 1024 + lane * 8; \
    gll16(asrc, &As[b][w * 1024]); \
    gll16(asrc + 512, &As[b][w * 1024 + 512]); \
    gll16(bb0 + (size_t)(kt) * 2048 + w * 512 + lane * 8, &BdS[b][w * 512]); \
    gll16(bb1 + (size_t)(kt) * 2048 + w * 512 + lane * 8, &BdS[b][2048 + w * 512]); \
  } while (0)

  int k0 = kh * 16;   // 16 K-steps (512 k-elems) per quarter
  STAGE2(k0, 0);
  __syncthreads();
  for (int kk = 0; kk < 16; kk++) {
    int cur = kk & 1;
    if (kk < 15) STAGE2(k0 + kk + 1, cur ^ 1);
    bf16x8 af[4];
#pragma unroll
    for (int mi = 0; mi < 4; mi++)
      af[mi] = *(const bf16x8*)&As[cur][quad * 1024 + (wm * 64 + mi * 16 + l15) * 8];
#pragma unroll
    for (int ni = 0; ni < 4; ni++) {
      bf16x8 bd = *(const bf16x8*)&BdS[cur][wn * 2048 + quad * 512 + (ni * 16 + l15) * 8];
#pragma unroll
      for (int mi = 0; mi < 4; mi++)
        acc[mi][ni] = __builtin_amdgcn_mfma_f32_16x16x32_bf16(af[mi], bd, acc[mi][ni], 0, 0, 0);
    }
    __syncthreads();
  }
#undef STAGE2

  // epilogue: weighted fp32 atomic scatter (all 4 k-quarters accumulate)
  int rem = cnt_e - mt * 128;
#pragma unroll
  for (int mi = 0; mi < 4; mi++)
#pragma unroll
    for (int r = 0; r < 4; r++) {
      int row = wm * 64 + mi * 16 + quad * 4 + r;
      if (row < rem) {
        int g = po + mt * 128 + row;
        int tt = tok[g];
        float wt = wgt[g];
#pragma unroll
        for (int ni = 0; ni < 4; ni++) {
          int col = nt * 128 + wn * 64 + ni * 16 + l15;
          atomicAdd(&out[(size_t)tt * H_ + col], wt * acc[mi][ni][r]);
        }
      }
    }
}

extern "C" void kernel_launch(void* const* d_in, const int* in_sizes, int n_in,
                              void* d_out, int out_size, void* d_ws, size_t ws_size,
                              hipStream_t stream) {
  const float* x  = (const float*)d_in[0];
  const float* rw = (const float*)d_in[1];
  const float* eg = (const float*)d_in[2];
  const float* eu = (const float*)d_in[3];
  const float* ed = (const float*)d_in[4];
  const float* sg = (const float*)d_in[5];
  const float* su = (const float*)d_in[6];
  const float* sd = (const float*)d_in[7];
  float* out = (float*)d_out;
  char* ws = (char*)d_ws;

  int*   cnt  = (int*)(ws + 64);
  int*   poffs= (int*)(ws + 128);
  int*   cur  = (int*)(ws + 256);
  int*   topi = (int*)(ws + 4096);
  float* topw = (float*)(ws + 4096 + 16384);
  int*   tok  = (int*)(ws + 36864);
  float* wgt  = (float*)(ws + 66560);
  unsigned short* apack = (unsigned short*)(ws + 131072);                 // 14.68 MB
  unsigned short* hbuf  = (unsigned short*)(ws + 131072 + 14811136);      // 29.36 MB used max
  float* probs = (float*)(ws + 44302336);   // tail slack of hbuf region (64 KB)
  float* lse2  = (float*)(ws + 44367872);   // 8 KB
  unsigned short* wgp   = (unsigned short*)(ws + 131072 + 14811136 + 29491200);
  unsigned short* wup   = (unsigned short*)((char*)wgp + (size_t)NE_ * H_ * I_ * 2);
  unsigned short* wdp   = (unsigned short*)((char*)wup + (size_t)NE_ * H_ * I_ * 2);

  hipMemsetAsync(ws, 0, 4096, stream);
  hipMemsetAsync(out, 0, (size_t)T_ * H_ * 4, stream);

  dim3 gp(64, 32, 3 * NE_);
  k_pack<<<gp, 256, 0, stream>>>(eg, eu, ed, sg, su, sd, wgp, wup, wdp);
  k_router<<<512, 256, 0, stream>>>(x, rw, topi, topw, probs, lse2);
  k_reduce<<<1, 256, 0, stream>>>(probs, lse2, topi, cnt, poffs, out + (size_t)T_ * H_);
  k_fill<<<8, 256, 0, stream>>>(topi, topw, poffs, cur, tok, wgt);
  dim3 ga(8, 16, NE_);
  k_packA<<<ga, 256, 0, stream>>>(x, cnt, poffs, tok, apack);
  k_gemm1<<<G1_GRID, 256, 0, stream>>>(apack, wgp, wup, cnt, poffs, hbuf);
  k_gemm2<<<G2_GRID, 256, 0, stream>>>(hbuf, wdp, cnt, poffs, tok, wgt, out);
}

// Round 4
// 438.451 us; speedup vs baseline: 1.0692x; 1.0692x over previous
//
#include <hip/hip_runtime.h>
#include <hip/hip_bf16.h>
#include <stdint.h>

#define T_ 2048
#define H_ 1024
#define I_ 2048
#define E_ 8
#define NE_ 9            // 8 routed + 1 shared (virtual expert)

typedef __attribute__((ext_vector_type(8))) short bf16x8;
typedef __attribute__((ext_vector_type(4))) float f32x4;

__device__ __forceinline__ unsigned short f2bf(float f) {
  unsigned int u; __builtin_memcpy(&u, &f, 4);
  u = (u + 0x7fffu + ((u >> 16) & 1u)) >> 16;
  return (unsigned short)u;
}
__device__ __forceinline__ void cvt2(float a, float b, unsigned short* dst) {
  __hip_bfloat162 h = __float22bfloat162_rn(float2{a, b});
  __builtin_memcpy(dst, &h, 4);
}
// async global->LDS DMA, 16B per lane; LDS dest = wave-uniform base + lane*16
__device__ __forceinline__ void gll16(const void* g, void* l) {
  __builtin_amdgcn_global_load_lds((const __attribute__((address_space(1))) void*)g,
                                   (__attribute__((address_space(3))) void*)l, 16, 0, 0);
}

// ---------------- pack weights: fp32 [K][N] -> bf16 blocked [nt64][kt32][q][nn][8] ----------------
__global__ __launch_bounds__(256) void k_pack(
    const float* __restrict__ eg, const float* __restrict__ eu, const float* __restrict__ ed,
    const float* __restrict__ sg, const float* __restrict__ su, const float* __restrict__ sd,
    unsigned short* __restrict__ wgp, unsigned short* __restrict__ wup,
    unsigned short* __restrict__ wdp) {
  int kt = blockIdx.x, nt = blockIdx.y, z = blockIdx.z;
  int grp = z / NE_, e = z % NE_;
  int K = (grp == 2) ? I_ : H_;
  int N = (grp == 2) ? H_ : I_;
  if (kt * 32 >= K || nt * 64 >= N) return;
  const float* src; unsigned short* dst;
  if (grp == 0)      { src = (e < E_) ? eg + (size_t)e * H_ * I_ : sg; dst = wgp + (size_t)e * H_ * I_; }
  else if (grp == 1) { src = (e < E_) ? eu + (size_t)e * H_ * I_ : su; dst = wup + (size_t)e * H_ * I_; }
  else               { src = (e < E_) ? ed + (size_t)e * I_ * H_ : sd; dst = wdp + (size_t)e * I_ * H_; }

  __shared__ __align__(16) float lds[32 * 68];
  int t = threadIdx.x;
  const float* srcbase = src + (size_t)(kt * 32) * N + nt * 64;
  int r0 = t >> 4, c0 = (t & 15) * 4;
  float4 v0 = *(const float4*)(srcbase + (size_t)r0 * N + c0);
  float4 v1 = *(const float4*)(srcbase + (size_t)(r0 + 16) * N + c0);
  *(float4*)&lds[r0 * 68 + c0] = v0;
  *(float4*)&lds[(r0 + 16) * 68 + c0] = v1;
  __syncthreads();

  int q = t >> 6, nn = t & 63;
  unsigned short o[8];
#pragma unroll
  for (int j = 0; j < 8; j += 2) {
    float a = lds[(q * 8 + j) * 68 + nn];
    float b = lds[(q * 8 + j + 1) * 68 + nn];
    cvt2(a, b, &o[j]);
  }
  size_t tile = ((size_t)nt * (K / 32) + kt) * 2048;
  *(bf16x8*)&dst[tile + q * 512 + nn * 8] = *(bf16x8*)o;
}

// ---------------- router: zero `out` slice + 1 wave per token ----------------
__global__ __launch_bounds__(256) void k_router(
    const float* __restrict__ x, const float* __restrict__ rw,
    int* __restrict__ topi, float* __restrict__ topw,
    float* __restrict__ probs, float* __restrict__ lse2,
    float* __restrict__ outz) {
  int tid = threadIdx.x;
  // fold the 8.4MB out-memset into this kernel: 512 blocks x 16KB
  {
    float4 zf = {0.f, 0.f, 0.f, 0.f};
    float4* ob = (float4*)(outz + (size_t)blockIdx.x * 4096);
#pragma unroll
    for (int i = 0; i < 4; i++) ob[i * 256 + tid] = zf;
  }
  __shared__ float lrw[E_ * H_];  // transposed [e][h], 32 KB
#pragma unroll
  for (int i = 0; i < 8; i++) {
    int idx = i * 256 + tid;          // float4 index over 2048
    float4 v = ((const float4*)rw)[idx];
    int f = idx * 4; int h = f >> 3; int e0 = f & 7;   // e0 in {0,4}
    lrw[(e0 + 0) * H_ + h] = v.x;
    lrw[(e0 + 1) * H_ + h] = v.y;
    lrw[(e0 + 2) * H_ + h] = v.z;
    lrw[(e0 + 3) * H_ + h] = v.w;
  }
  __syncthreads();
  int w = tid >> 6, lane = tid & 63;
  int t = blockIdx.x * 4 + w;
  const float* xp = x + (size_t)t * H_ + lane;
  float xr[16];
#pragma unroll
  for (int j = 0; j < 16; j++) xr[j] = xp[j * 64];   // coalesced dword loads
  float acc[E_];
#pragma unroll
  for (int e = 0; e < E_; e++) acc[e] = 0.f;
#pragma unroll
  for (int j = 0; j < 16; j++) {
    float xf = xr[j];
    const float* wp = &lrw[j * 64 + lane];           // lane-stride 1 -> conflict-free
#pragma unroll
    for (int e = 0; e < E_; e++) acc[e] += xf * wp[e * H_];
  }
#pragma unroll
  for (int off = 32; off >= 1; off >>= 1) {
#pragma unroll
    for (int e = 0; e < E_; e++) acc[e] += __shfl_xor(acc[e], off, 64);
  }
  if (lane == 0) {
    float m = acc[0];
#pragma unroll
    for (int e = 1; e < E_; e++) m = fmaxf(m, acc[e]);
    float p[E_], s = 0.f;
#pragma unroll
    for (int e = 0; e < E_; e++) { p[e] = expf(acc[e] - m); s += p[e]; }
    float inv = 1.f / s;
#pragma unroll
    for (int e = 0; e < E_; e++) p[e] *= inv;
    float lse = m + logf(s);
    lse2[t] = lse * lse;
    float4 p0 = {p[0], p[1], p[2], p[3]}, p1 = {p[4], p[5], p[6], p[7]};
    ((float4*)(probs + t * 8))[0] = p0;
    ((float4*)(probs + t * 8))[1] = p1;
    int i0 = 0;
#pragma unroll
    for (int e = 1; e < E_; e++) if (p[e] > p[i0]) i0 = e;
    int i1 = (i0 == 0) ? 1 : 0;
#pragma unroll
    for (int e = 0; e < E_; e++) if (e != i0 && e != i1 && p[e] > p[i1]) i1 = e;
    float w0 = p[i0], w1 = p[i1], wsum = w0 + w1;
    topi[t * 2] = i0; topi[t * 2 + 1] = i1;
    topw[t * 2] = w0 / wsum; topw[t * 2 + 1] = w1 / wsum;
  }
}

// ---------------- sched: reduce (cnt/poffs/aux) + fill (tok/wgt), one block ----------------
__global__ __launch_bounds__(256) void k_sched(
    const float* __restrict__ probs, const float* __restrict__ lse2,
    const int* __restrict__ topi, const float* __restrict__ topw,
    int* cnt, int* poffs, float* out_aux,
    int* __restrict__ tok, float* __restrict__ wgt) {
  __shared__ float sp[256][9];
  __shared__ int sc[256][8];
  __shared__ int sbase[NE_];
  __shared__ int scur[8];
  int tid = threadIdx.x;
  float ps[9] = {0.f, 0.f, 0.f, 0.f, 0.f, 0.f, 0.f, 0.f, 0.f};
  int c[8] = {0, 0, 0, 0, 0, 0, 0, 0};
  for (int t = tid; t < T_; t += 256) {
#pragma unroll
    for (int e = 0; e < E_; e++) ps[e] += probs[t * 8 + e];
    ps[8] += lse2[t];
    c[topi[t * 2]]++; c[topi[t * 2 + 1]]++;
  }
#pragma unroll
  for (int e = 0; e < 9; e++) sp[tid][e] = ps[e];
#pragma unroll
  for (int e = 0; e < 8; e++) sc[tid][e] = c[e];
  __syncthreads();
  for (int s = 128; s > 0; s >>= 1) {
    if (tid < s) {
#pragma unroll
      for (int e = 0; e < 9; e++) sp[tid][e] += sp[tid + s][e];
#pragma unroll
      for (int e = 0; e < 8; e++) sc[tid][e] += sc[tid + s][e];
    }
    __syncthreads();
  }
  if (tid == 0) {
#pragma unroll
    for (int e = 0; e < E_; e++) cnt[e] = sc[0][e];
    cnt[E_] = T_;
    int po = 0;
    for (int e = 0; e < NE_; e++) {
      poffs[e] = po; sbase[e] = po;
      int ce = (e < E_) ? sc[0][e] : T_;
      po += ((ce + 127) >> 7) << 7;
    }
    poffs[NE_] = po;
    float lb = 0.f;
#pragma unroll
    for (int e = 0; e < E_; e++)
      lb += ((float)sc[0][e] / 4096.f) * (sp[0][e] / 2048.f);
    out_aux[0] = 0.01f * 8.f * lb + 0.001f * (sp[0][8] / 2048.f);
  }
  if (tid < 8) scur[tid] = 0;
  __syncthreads();
  for (int t = tid; t < T_; t += 256) {
    int e0 = topi[t * 2], e1 = topi[t * 2 + 1];
    int p0 = atomicAdd(&scur[e0], 1);
    int p1 = atomicAdd(&scur[e1], 1);
    tok[sbase[e0] + p0] = t; wgt[sbase[e0] + p0] = topw[t * 2];
    tok[sbase[e1] + p1] = t; wgt[sbase[e1] + p1] = topw[t * 2 + 1];
    tok[sbase[E_] + t] = t; wgt[sbase[E_] + t] = 1.f;
  }
}

// ---------------- packA: gather x rows -> bf16 blocked A [rt][kt][q][m][8] ----------------
__global__ __launch_bounds__(256) void k_packA(
    const float* __restrict__ x, const int* __restrict__ cnt,
    const int* __restrict__ poffs, const int* __restrict__ tok,
    unsigned short* __restrict__ apack) {
  int kc = blockIdx.x, mt = blockIdx.y, e = blockIdx.z;
  int cnt_e = cnt[e];
  if (mt * 128 >= cnt_e) return;
  int po = poffs[e];
  int rt = (po >> 7) + mt;
  int t = threadIdx.x;
  int m = t & 127, qh = t >> 7;
  int atok = tok[po + min(mt * 128 + m, cnt_e - 1)];
  const float* arow = x + (size_t)atok * H_;
  size_t abase = (size_t)rt * 32 * 4096;
#pragma unroll
  for (int ki = 0; ki < 4; ki++) {
    int kt = kc * 4 + ki;
#pragma unroll
    for (int qo = 0; qo < 2; qo++) {
      int q = qh + qo * 2;
      const float* s = arow + kt * 32 + q * 8;
      float4 v0 = *(const float4*)s, v1 = *(const float4*)(s + 4);
      unsigned short t8[8];
      cvt2(v0.x, v0.y, t8); cvt2(v0.z, v0.w, t8 + 2);
      cvt2(v1.x, v1.y, t8 + 4); cvt2(v1.z, v1.w, t8 + 6);
      *(bf16x8*)&apack[abase + (size_t)kt * 4096 + q * 1024 + m * 8] = *(bf16x8*)t8;
    }
  }
}

// ---------------- GEMM1: h = silu(x*Wg)*(x*Wu) ----------------
// 3-buffer LDS, depth-2 prefetch, counted vmcnt(4) across raw barriers
// (4 gll16 per stage; never drain to 0 in the steady state).
#define G1_GRID 1792   // 56 rt-slots * 32 nt, multiple of 8
__global__ __launch_bounds__(256) void k_gemm1(
    const unsigned short* __restrict__ apack,
    const unsigned short* __restrict__ wgp, const unsigned short* __restrict__ wup,
    const int* __restrict__ cnt, const int* __restrict__ poffs,
    unsigned short* __restrict__ hbuf) {
  int lin = blockIdx.x;
  int s = (lin & 7) * (G1_GRID / 8) + (lin >> 3);   // bijective XCD chunk swizzle
  int rt = s >> 5, nt = s & 31;
  int rtTotal = poffs[NE_] >> 7;
  if (rt >= rtTotal) return;
  int ro = rt << 7;
  int e = 0;
#pragma unroll
  for (int i = 1; i < NE_; i++) if (poffs[i] <= ro) e = i;
  int po = poffs[e];
  int cnt_e = cnt[e];
  int mt = (ro - po) >> 7;

  __shared__ __align__(16) unsigned short As[3][4096];   // [q][m][8]
  __shared__ __align__(16) unsigned short BgS[3][2048];  // [q][nn][8]
  __shared__ __align__(16) unsigned short BuS[3][2048];

  int tid = threadIdx.x;
  int lane = tid & 63, w = tid >> 6;
  int quad = lane >> 4, l15 = lane & 15;
  int wm = w >> 1, wn = w & 1;

  const unsigned short* abase = apack + (size_t)rt * 32 * 4096;
  const unsigned short* bgb = wgp + (size_t)e * H_ * I_ + (size_t)nt * 32 * 2048;
  const unsigned short* bub = wup + (size_t)e * H_ * I_ + (size_t)nt * 32 * 2048;

  f32x4 zero = {0.f, 0.f, 0.f, 0.f};
  f32x4 accg[4][2], accu[4][2];
#pragma unroll
  for (int mi = 0; mi < 4; mi++)
#pragma unroll
    for (int ni = 0; ni < 2; ni++) { accg[mi][ni] = zero; accu[mi][ni] = zero; }

#define STAGE1(kt, b) do { \
    const unsigned short* asrc = abase + (size_t)(kt) * 4096 + w * 1024 + lane * 8; \
    gll16(asrc, &As[b][w * 1024]); \
    gll16(asrc + 512, &As[b][w * 1024 + 512]); \
    gll16(bgb + (size_t)(kt) * 2048 + w * 512 + lane * 8, &BgS[b][w * 512]); \
    gll16(bub + (size_t)(kt) * 2048 + w * 512 + lane * 8, &BuS[b][w * 512]); \
  } while (0)

#define COMP1(b) do { \
    bf16x8 af[4]; \
    _Pragma("unroll") \
    for (int mi = 0; mi < 4; mi++) \
      af[mi] = *(const bf16x8*)&As[b][quad * 1024 + (wm * 64 + mi * 16 + l15) * 8]; \
    _Pragma("unroll") \
    for (int ni = 0; ni < 2; ni++) { \
      bf16x8 bg = *(const bf16x8*)&BgS[b][quad * 512 + (wn * 32 + ni * 16 + l15) * 8]; \
      bf16x8 bu = *(const bf16x8*)&BuS[b][quad * 512 + (wn * 32 + ni * 16 + l15) * 8]; \
      _Pragma("unroll") \
      for (int mi = 0; mi < 4; mi++) { \
        accg[mi][ni] = __builtin_amdgcn_mfma_f32_16x16x32_bf16(af[mi], bg, accg[mi][ni], 0, 0, 0); \
        accu[mi][ni] = __builtin_amdgcn_mfma_f32_16x16x32_bf16(af[mi], bu, accu[mi][ni], 0, 0, 0); \
      } \
    } \
  } while (0)

#define WAIT4 asm volatile("s_waitcnt vmcnt(4)" ::: "memory")
#define WAIT0 asm volatile("s_waitcnt vmcnt(0)" ::: "memory")
#define BAR __builtin_amdgcn_s_barrier()

  STAGE1(0, 0); STAGE1(1, 1);
  WAIT4; BAR;                      // stage 0 complete (stage 1 may be in flight)
  for (int it = 0; it < 10; ++it) {
    int kt = it * 3;
    STAGE1(kt + 2, 2); COMP1(0); WAIT4; BAR;   // kt   computed; kt+1 ready
    STAGE1(kt + 3, 0); COMP1(1); WAIT4; BAR;   // kt+1 computed; kt+2 ready
    STAGE1(kt + 4, 1); COMP1(2); WAIT4; BAR;   // kt+2 computed; kt+3 ready
  }
  COMP1(0);                         // kt = 30
  WAIT0; BAR;                       // stage 31 complete
  COMP1(1);                         // kt = 31
#undef STAGE1
#undef COMP1

  // epilogue: silu(g)*u -> hbuf in gemm2's packed-A layout [rt][kt2][q2][m][8]
  size_t hbase = (size_t)rt * 64 * 4096;
  int rem = cnt_e - mt * 128;
#pragma unroll
  for (int ni = 0; ni < 2; ni++) {
    int cc = nt * 64 + wn * 32 + ni * 16 + l15;
    size_t cb = hbase + (size_t)(cc >> 5) * 4096 + (size_t)((cc >> 3) & 3) * 1024 + (cc & 7);
#pragma unroll
    for (int mi = 0; mi < 4; mi++)
#pragma unroll
      for (int r = 0; r < 4; r++) {
        int row = wm * 64 + mi * 16 + quad * 4 + r;
        if (row < rem) {
          float g = accg[mi][ni][r], u = accu[mi][ni][r];
          float sv = g / (1.f + __expf(-g));
          hbuf[cb + (size_t)row * 8] = f2bf(sv * u);
        }
      }
  }
}

// ---------------- GEMM2: out += w * (h * Wd); K-split x2, 3-buf counted vmcnt ----------------
#define G2_GRID 896    // 56 rt-slots * 8 nt * 2 khalf, multiple of 8
__global__ __launch_bounds__(256) void k_gemm2(
    const unsigned short* __restrict__ hbuf, const unsigned short* __restrict__ wdp,
    const int* __restrict__ cnt, const int* __restrict__ poffs,
    const int* __restrict__ tok, const float* __restrict__ wgt,
    float* __restrict__ out) {
  int lin = blockIdx.x;
  int s = (lin & 7) * (G2_GRID / 8) + (lin >> 3);   // bijective XCD chunk swizzle
  int rt = s >> 4;
  int r4 = s & 15;
  int nt = r4 >> 1, kh = r4 & 1;
  int rtTotal = poffs[NE_] >> 7;
  if (rt >= rtTotal) return;
  int ro = rt << 7;
  int e = 0;
#pragma unroll
  for (int i = 1; i < NE_; i++) if (poffs[i] <= ro) e = i;
  int po = poffs[e];
  int cnt_e = cnt[e];
  int mt = (ro - po) >> 7;

  __shared__ __align__(16) unsigned short As[3][4096];   // [q][m][8]
  __shared__ __align__(16) unsigned short BdS[3][4096];  // [h][q][nn][8]

  int tid = threadIdx.x;
  int lane = tid & 63, w = tid >> 6;
  int quad = lane >> 4, l15 = lane & 15;
  int wm = w >> 1, wn = w & 1;

  int k0 = kh * 32;
  const unsigned short* abase = hbuf + (size_t)rt * 64 * 4096;
  const unsigned short* bb0 = wdp + (size_t)e * I_ * H_ + ((size_t)(2 * nt) * 64) * 2048;
  const unsigned short* bb1 = wdp + (size_t)e * I_ * H_ + ((size_t)(2 * nt + 1) * 64) * 2048;

  f32x4 zero = {0.f, 0.f, 0.f, 0.f};
  f32x4 acc[4][4];
#pragma unroll
  for (int mi = 0; mi < 4; mi++)
#pragma unroll
    for (int ni = 0; ni < 4; ni++) acc[mi][ni] = zero;

#define STAGE2(kk, b) do { \
    const unsigned short* asrc = abase + (size_t)(k0 + (kk)) * 4096 + w * 1024 + lane * 8; \
    gll16(asrc, &As[b][w * 1024]); \
    gll16(asrc + 512, &As[b][w * 1024 + 512]); \
    gll16(bb0 + (size_t)(k0 + (kk)) * 2048 + w * 512 + lane * 8, &BdS[b][w * 512]); \
    gll16(bb1 + (size_t)(k0 + (kk)) * 2048 + w * 512 + lane * 8, &BdS[b][2048 + w * 512]); \
  } while (0)

#define COMP2(b) do { \
    bf16x8 af[4]; \
    _Pragma("unroll") \
    for (int mi = 0; mi < 4; mi++) \
      af[mi] = *(const bf16x8*)&As[b][quad * 1024 + (wm * 64 + mi * 16 + l15) * 8]; \
    _Pragma("unroll") \
    for (int ni = 0; ni < 4; ni++) { \
      bf16x8 bd = *(const bf16x8*)&BdS[b][wn * 2048 + quad * 512 + (ni * 16 + l15) * 8]; \
      _Pragma("unroll") \
      for (int mi = 0; mi < 4; mi++) \
        acc[mi][ni] = __builtin_amdgcn_mfma_f32_16x16x32_bf16(af[mi], bd, acc[mi][ni], 0, 0, 0); \
    } \
  } while (0)

  STAGE2(0, 0); STAGE2(1, 1);
  WAIT4; BAR;
  for (int it = 0; it < 10; ++it) {
    int kk = it * 3;
    STAGE2(kk + 2, 2); COMP2(0); WAIT4; BAR;
    STAGE2(kk + 3, 0); COMP2(1); WAIT4; BAR;
    STAGE2(kk + 4, 1); COMP2(2); WAIT4; BAR;
  }
  COMP2(0);                         // kk = 30
  WAIT0; BAR;
  COMP2(1);                         // kk = 31
#undef STAGE2
#undef COMP2

  // epilogue: weighted fp32 atomic scatter (both k-halves accumulate)
  int rem = cnt_e - mt * 128;
#pragma unroll
  for (int mi = 0; mi < 4; mi++)
#pragma unroll
    for (int r = 0; r < 4; r++) {
      int row = wm * 64 + mi * 16 + quad * 4 + r;
      if (row < rem) {
        int g = po + mt * 128 + row;
        int tt = tok[g];
        float wt = wgt[g];
#pragma unroll
        for (int ni = 0; ni < 4; ni++) {
          int col = nt * 128 + wn * 64 + ni * 16 + l15;
          atomicAdd(&out[(size_t)tt * H_ + col], wt * acc[mi][ni][r]);
        }
      }
    }
}

extern "C" void kernel_launch(void* const* d_in, const int* in_sizes, int n_in,
                              void* d_out, int out_size, void* d_ws, size_t ws_size,
                              hipStream_t stream) {
  const float* x  = (const float*)d_in[0];
  const float* rw = (const float*)d_in[1];
  const float* eg = (const float*)d_in[2];
  const float* eu = (const float*)d_in[3];
  const float* ed = (const float*)d_in[4];
  const float* sg = (const float*)d_in[5];
  const float* su = (const float*)d_in[6];
  const float* sd = (const float*)d_in[7];
  float* out = (float*)d_out;
  char* ws = (char*)d_ws;

  int*   cnt  = (int*)(ws + 64);
  int*   poffs= (int*)(ws + 128);
  int*   topi = (int*)(ws + 4096);
  float* topw = (float*)(ws + 4096 + 16384);
  int*   tok  = (int*)(ws + 36864);
  float* wgt  = (float*)(ws + 66560);
  unsigned short* apack = (unsigned short*)(ws + 131072);                 // 14.68 MB
  unsigned short* hbuf  = (unsigned short*)(ws + 131072 + 14811136);      // 29.36 MB used max
  float* probs = (float*)(ws + 44302336);   // tail slack of hbuf region (64 KB)
  float* lse2  = (float*)(ws + 44367872);   // 8 KB
  unsigned short* wgp   = (unsigned short*)(ws + 131072 + 14811136 + 29491200);
  unsigned short* wup   = (unsigned short*)((char*)wgp + (size_t)NE_ * H_ * I_ * 2);
  unsigned short* wdp   = (unsigned short*)((char*)wup + (size_t)NE_ * H_ * I_ * 2);

  dim3 gp(64, 32, 3 * NE_);
  k_pack<<<gp, 256, 0, stream>>>(eg, eu, ed, sg, su, sd, wgp, wup, wdp);
  k_router<<<512, 256, 0, stream>>>(x, rw, topi, topw, probs, lse2, out);
  k_sched<<<1, 256, 0, stream>>>(probs, lse2, topi, topw, cnt, poffs,
                                 out + (size_t)T_ * H_, tok, wgt);
  dim3 ga(8, 16, NE_);
  k_packA<<<ga, 256, 0, stream>>>(x, cnt, poffs, tok, apack);
  k_gemm1<<<G1_GRID, 256, 0, stream>>>(apack, wgp, wup, cnt, poffs, hbuf);
  k_gemm2<<<G2_GRID, 256, 0, stream>>>(hbuf, wdp, cnt, poffs, tok, wgt, out);
}

// Round 5
// 426.402 us; speedup vs baseline: 1.0994x; 1.0283x over previous
//
#include <hip/hip_runtime.h>
#include <hip/hip_bf16.h>
#include <stdint.h>

#define T_ 2048
#define H_ 1024
#define I_ 2048
#define E_ 8
#define NE_ 9            // 8 routed + 1 shared (virtual expert)

typedef __attribute__((ext_vector_type(8))) short bf16x8;
typedef __attribute__((ext_vector_type(4))) float f32x4;

__device__ __forceinline__ unsigned short f2bf(float f) {
  unsigned int u; __builtin_memcpy(&u, &f, 4);
  u = (u + 0x7fffu + ((u >> 16) & 1u)) >> 16;
  return (unsigned short)u;
}
__device__ __forceinline__ void cvt2(float a, float b, unsigned short* dst) {
  __hip_bfloat162 h = __float22bfloat162_rn(float2{a, b});
  __builtin_memcpy(dst, &h, 4);
}
// async global->LDS DMA, 16B per lane; LDS dest = wave-uniform base + lane*16
__device__ __forceinline__ void gll16(const void* g, void* l) {
  __builtin_amdgcn_global_load_lds((const __attribute__((address_space(1))) void*)g,
                                   (__attribute__((address_space(3))) void*)l, 16, 0, 0);
}

// ---------------- router: zero `out` slice + 1 wave per token ----------------
__global__ __launch_bounds__(256) void k_router(
    const float* __restrict__ x, const float* __restrict__ rw,
    int* __restrict__ topi, float* __restrict__ topw,
    float* __restrict__ probs, float* __restrict__ lse2,
    float* __restrict__ outz) {
  int tid = threadIdx.x;
  // fold the 8.4MB out-memset into this kernel: 512 blocks x 16KB
  {
    float4 zf = {0.f, 0.f, 0.f, 0.f};
    float4* ob = (float4*)(outz + (size_t)blockIdx.x * 4096);
#pragma unroll
    for (int i = 0; i < 4; i++) ob[i * 256 + tid] = zf;
  }
  __shared__ float lrw[E_ * H_];  // transposed [e][h], 32 KB
#pragma unroll
  for (int i = 0; i < 8; i++) {
    int idx = i * 256 + tid;          // float4 index over 2048
    float4 v = ((const float4*)rw)[idx];
    int f = idx * 4; int h = f >> 3; int e0 = f & 7;   // e0 in {0,4}
    lrw[(e0 + 0) * H_ + h] = v.x;
    lrw[(e0 + 1) * H_ + h] = v.y;
    lrw[(e0 + 2) * H_ + h] = v.z;
    lrw[(e0 + 3) * H_ + h] = v.w;
  }
  __syncthreads();
  int w = tid >> 6, lane = tid & 63;
  int t = blockIdx.x * 4 + w;
  const float* xp = x + (size_t)t * H_ + lane;
  float xr[16];
#pragma unroll
  for (int j = 0; j < 16; j++) xr[j] = xp[j * 64];   // coalesced dword loads
  float acc[E_];
#pragma unroll
  for (int e = 0; e < E_; e++) acc[e] = 0.f;
#pragma unroll
  for (int j = 0; j < 16; j++) {
    float xf = xr[j];
    const float* wp = &lrw[j * 64 + lane];           // lane-stride 1 -> conflict-free
#pragma unroll
    for (int e = 0; e < E_; e++) acc[e] += xf * wp[e * H_];
  }
#pragma unroll
  for (int off = 32; off >= 1; off >>= 1) {
#pragma unroll
    for (int e = 0; e < E_; e++) acc[e] += __shfl_xor(acc[e], off, 64);
  }
  if (lane == 0) {
    float m = acc[0];
#pragma unroll
    for (int e = 1; e < E_; e++) m = fmaxf(m, acc[e]);
    float p[E_], s = 0.f;
#pragma unroll
    for (int e = 0; e < E_; e++) { p[e] = expf(acc[e] - m); s += p[e]; }
    float inv = 1.f / s;
#pragma unroll
    for (int e = 0; e < E_; e++) p[e] *= inv;
    float lse = m + logf(s);
    lse2[t] = lse * lse;
    float4 p0 = {p[0], p[1], p[2], p[3]}, p1 = {p[4], p[5], p[6], p[7]};
    ((float4*)(probs + t * 8))[0] = p0;
    ((float4*)(probs + t * 8))[1] = p1;
    int i0 = 0;
#pragma unroll
    for (int e = 1; e < E_; e++) if (p[e] > p[i0]) i0 = e;
    int i1 = (i0 == 0) ? 1 : 0;
#pragma unroll
    for (int e = 0; e < E_; e++) if (e != i0 && e != i1 && p[e] > p[i1]) i1 = e;
    float w0 = p[i0], w1 = p[i1], wsum = w0 + w1;
    topi[t * 2] = i0; topi[t * 2 + 1] = i1;
    topw[t * 2] = w0 / wsum; topw[t * 2 + 1] = w1 / wsum;
  }
}

// ---------------- sched: reduce (cnt/poffs/aux) + fill (tok/wgt), one block ----------------
__global__ __launch_bounds__(256) void k_sched(
    const float* __restrict__ probs, const float* __restrict__ lse2,
    const int* __restrict__ topi, const float* __restrict__ topw,
    int* cnt, int* poffs, float* out_aux,
    int* __restrict__ tok, float* __restrict__ wgt) {
  __shared__ float sp[256][9];
  __shared__ int sc[256][8];
  __shared__ int sbase[NE_];
  __shared__ int scur[8];
  int tid = threadIdx.x;
  float ps[9] = {0.f, 0.f, 0.f, 0.f, 0.f, 0.f, 0.f, 0.f, 0.f};
  int c[8] = {0, 0, 0, 0, 0, 0, 0, 0};
  for (int t = tid; t < T_; t += 256) {
#pragma unroll
    for (int e = 0; e < E_; e++) ps[e] += probs[t * 8 + e];
    ps[8] += lse2[t];
    c[topi[t * 2]]++; c[topi[t * 2 + 1]]++;
  }
#pragma unroll
  for (int e = 0; e < 9; e++) sp[tid][e] = ps[e];
#pragma unroll
  for (int e = 0; e < 8; e++) sc[tid][e] = c[e];
  __syncthreads();
  for (int s = 128; s > 0; s >>= 1) {
    if (tid < s) {
#pragma unroll
      for (int e = 0; e < 9; e++) sp[tid][e] += sp[tid + s][e];
#pragma unroll
      for (int e = 0; e < 8; e++) sc[tid][e] += sc[tid + s][e];
    }
    __syncthreads();
  }
  if (tid == 0) {
#pragma unroll
    for (int e = 0; e < E_; e++) cnt[e] = sc[0][e];
    cnt[E_] = T_;
    int po = 0;
    for (int e = 0; e < NE_; e++) {
      poffs[e] = po; sbase[e] = po;
      int ce = (e < E_) ? sc[0][e] : T_;
      po += ((ce + 127) >> 7) << 7;
    }
    poffs[NE_] = po;
    float lb = 0.f;
#pragma unroll
    for (int e = 0; e < E_; e++)
      lb += ((float)sc[0][e] / 4096.f) * (sp[0][e] / 2048.f);
    out_aux[0] = 0.01f * 8.f * lb + 0.001f * (sp[0][8] / 2048.f);
  }
  if (tid < 8) scur[tid] = 0;
  __syncthreads();
  for (int t = tid; t < T_; t += 256) {
    int e0 = topi[t * 2], e1 = topi[t * 2 + 1];
    int p0 = atomicAdd(&scur[e0], 1);
    int p1 = atomicAdd(&scur[e1], 1);
    tok[sbase[e0] + p0] = t; wgt[sbase[e0] + p0] = topw[t * 2];
    tok[sbase[e1] + p1] = t; wgt[sbase[e1] + p1] = topw[t * 2 + 1];
    tok[sbase[E_] + t] = t; wgt[sbase[E_] + t] = 1.f;
  }
}

// ---------------- prep: fused weight-pack + A-pack (independent halves) ----------------
// pack: 27 matrices x 1024 tiles, nt-FASTEST decode so 32 consecutive blocks
//       stream whole 8KB rows contiguously (HBM-friendly).
// packA: gather x rows -> bf16 blocked A (needs sched's tok/poffs).
#define PACK_BLKS 27648   // 27 * 1024
#define PREP_GRID 28800   // + 8*16*9 packA blocks
__global__ __launch_bounds__(256) void k_prep(
    const float* __restrict__ eg, const float* __restrict__ eu, const float* __restrict__ ed,
    const float* __restrict__ sg, const float* __restrict__ su, const float* __restrict__ sd,
    unsigned short* __restrict__ wgp, unsigned short* __restrict__ wup,
    unsigned short* __restrict__ wdp,
    const float* __restrict__ x, const int* __restrict__ cnt,
    const int* __restrict__ poffs, const int* __restrict__ tok,
    unsigned short* __restrict__ apack) {
  __shared__ __align__(16) float lds[32 * 68];
  int bz = blockIdx.x;
  int t = threadIdx.x;
  if (bz < PACK_BLKS) {
    int mat = bz >> 10, tile = bz & 1023;
    int grp = mat / NE_, e = mat % NE_;
    int K, N, kt, nt;
    if (grp == 2) { K = I_; N = H_; kt = tile >> 4; nt = tile & 15; }
    else          { K = H_; N = I_; kt = tile >> 5; nt = tile & 31; }
    const float* src; unsigned short* dst;
    if (grp == 0)      { src = (e < E_) ? eg + (size_t)e * H_ * I_ : sg; dst = wgp + (size_t)e * H_ * I_; }
    else if (grp == 1) { src = (e < E_) ? eu + (size_t)e * H_ * I_ : su; dst = wup + (size_t)e * H_ * I_; }
    else               { src = (e < E_) ? ed + (size_t)e * I_ * H_ : sd; dst = wdp + (size_t)e * I_ * H_; }

    const float* srcbase = src + (size_t)(kt * 32) * N + nt * 64;
    int r0 = t >> 4, c0 = (t & 15) * 4;
    float4 v0 = *(const float4*)(srcbase + (size_t)r0 * N + c0);
    float4 v1 = *(const float4*)(srcbase + (size_t)(r0 + 16) * N + c0);
    *(float4*)&lds[r0 * 68 + c0] = v0;
    *(float4*)&lds[(r0 + 16) * 68 + c0] = v1;
    __syncthreads();

    int q = t >> 6, nn = t & 63;
    unsigned short o[8];
#pragma unroll
    for (int j = 0; j < 8; j += 2) {
      float a = lds[(q * 8 + j) * 68 + nn];
      float b = lds[(q * 8 + j + 1) * 68 + nn];
      cvt2(a, b, &o[j]);
    }
    size_t tile_off = ((size_t)nt * (K / 32) + kt) * 2048;
    *(bf16x8*)&dst[tile_off + q * 512 + nn * 8] = *(bf16x8*)o;
  } else {
    int id = bz - PACK_BLKS;
    int kc = id & 7, mt = (id >> 3) & 15, e = id >> 7;
    int cnt_e = cnt[e];
    if (mt * 128 >= cnt_e) return;
    int po = poffs[e];
    int rt = (po >> 7) + mt;
    int m = t & 127, qh = t >> 7;
    int atok = tok[po + min(mt * 128 + m, cnt_e - 1)];
    const float* arow = x + (size_t)atok * H_;
    size_t abase = (size_t)rt * 32 * 4096;
#pragma unroll
    for (int ki = 0; ki < 4; ki++) {
      int kt = kc * 4 + ki;
#pragma unroll
      for (int qo = 0; qo < 2; qo++) {
        int q = qh + qo * 2;
        const float* s = arow + kt * 32 + q * 8;
        float4 v0 = *(const float4*)s, v1 = *(const float4*)(s + 4);
        unsigned short t8[8];
        cvt2(v0.x, v0.y, t8); cvt2(v0.z, v0.w, t8 + 2);
        cvt2(v1.x, v1.y, t8 + 4); cvt2(v1.z, v1.w, t8 + 6);
        *(bf16x8*)&apack[abase + (size_t)kt * 4096 + q * 1024 + m * 8] = *(bf16x8*)t8;
      }
    }
  }
}

// ---------------- GEMM1: h = silu(x*Wg)*(x*Wu) ----------------
// round-1 exact: 1-D compacted grid over (rt, nt), XCD-swizzled, 2-buffer
// dbuf prefetch (stage kt+1 while computing kt; ONE barrier per K-step).
#define G1_GRID 1792   // 56 rt-slots * 32 nt, multiple of 8
__global__ __launch_bounds__(256) void k_gemm1(
    const unsigned short* __restrict__ apack,
    const unsigned short* __restrict__ wgp, const unsigned short* __restrict__ wup,
    const int* __restrict__ cnt, const int* __restrict__ poffs,
    unsigned short* __restrict__ hbuf) {
  int lin = blockIdx.x;
  int s = (lin & 7) * (G1_GRID / 8) + (lin >> 3);   // bijective XCD chunk swizzle
  int rt = s >> 5, nt = s & 31;
  int rtTotal = poffs[NE_] >> 7;
  if (rt >= rtTotal) return;
  int ro = rt << 7;
  int e = 0;
#pragma unroll
  for (int i = 1; i < NE_; i++) if (poffs[i] <= ro) e = i;
  int po = poffs[e];
  int cnt_e = cnt[e];
  int mt = (ro - po) >> 7;

  __shared__ __align__(16) unsigned short As[2][4096];   // [q][m][8]
  __shared__ __align__(16) unsigned short BgS[2][2048];  // [q][nn][8]
  __shared__ __align__(16) unsigned short BuS[2][2048];

  int tid = threadIdx.x;
  int lane = tid & 63, w = tid >> 6;
  int quad = lane >> 4, l15 = lane & 15;
  int wm = w >> 1, wn = w & 1;

  const unsigned short* abase = apack + (size_t)rt * 32 * 4096;
  const unsigned short* bgb = wgp + (size_t)e * H_ * I_ + (size_t)nt * 32 * 2048;
  const unsigned short* bub = wup + (size_t)e * H_ * I_ + (size_t)nt * 32 * 2048;

  f32x4 zero = {0.f, 0.f, 0.f, 0.f};
  f32x4 accg[4][2], accu[4][2];
#pragma unroll
  for (int mi = 0; mi < 4; mi++)
#pragma unroll
    for (int ni = 0; ni < 2; ni++) { accg[mi][ni] = zero; accu[mi][ni] = zero; }

#define STAGE1(kt, b) do { \
    const unsigned short* asrc = abase + (size_t)(kt) * 4096 + w * 1024 + lane * 8; \
    gll16(asrc, &As[b][w * 1024]); \
    gll16(asrc + 512, &As[b][w * 1024 + 512]); \
    gll16(bgb + (size_t)(kt) * 2048 + w * 512 + lane * 8, &BgS[b][w * 512]); \
    gll16(bub + (size_t)(kt) * 2048 + w * 512 + lane * 8, &BuS[b][w * 512]); \
  } while (0)

  STAGE1(0, 0);
  __syncthreads();   // drains vmcnt(0): buf0 ready
  for (int kt = 0; kt < 32; kt++) {
    int cur = kt & 1;
    if (kt < 31) STAGE1(kt + 1, cur ^ 1);   // in flight under the compute below
    bf16x8 af[4];
#pragma unroll
    for (int mi = 0; mi < 4; mi++)
      af[mi] = *(const bf16x8*)&As[cur][quad * 1024 + (wm * 64 + mi * 16 + l15) * 8];
#pragma unroll
    for (int ni = 0; ni < 2; ni++) {
      bf16x8 bg = *(const bf16x8*)&BgS[cur][quad * 512 + (wn * 32 + ni * 16 + l15) * 8];
      bf16x8 bu = *(const bf16x8*)&BuS[cur][quad * 512 + (wn * 32 + ni * 16 + l15) * 8];
#pragma unroll
      for (int mi = 0; mi < 4; mi++) {
        accg[mi][ni] = __builtin_amdgcn_mfma_f32_16x16x32_bf16(af[mi], bg, accg[mi][ni], 0, 0, 0);
        accu[mi][ni] = __builtin_amdgcn_mfma_f32_16x16x32_bf16(af[mi], bu, accu[mi][ni], 0, 0, 0);
      }
    }
    __syncthreads();   // next buffer staged + everyone done reading cur
  }
#undef STAGE1

  // epilogue: silu(g)*u -> hbuf in gemm2's packed-A layout [rt][kt2][q2][m][8]
  size_t hbase = (size_t)rt * 64 * 4096;
  int rem = cnt_e - mt * 128;
#pragma unroll
  for (int ni = 0; ni < 2; ni++) {
    int cc = nt * 64 + wn * 32 + ni * 16 + l15;
    size_t cb = hbase + (size_t)(cc >> 5) * 4096 + (size_t)((cc >> 3) & 3) * 1024 + (cc & 7);
#pragma unroll
    for (int mi = 0; mi < 4; mi++)
#pragma unroll
      for (int r = 0; r < 4; r++) {
        int row = wm * 64 + mi * 16 + quad * 4 + r;
        if (row < rem) {
          float g = accg[mi][ni][r], u = accu[mi][ni][r];
          float sv = g / (1.f + __expf(-g));
          hbuf[cb + (size_t)row * 8] = f2bf(sv * u);
        }
      }
  }
}

// ---------------- GEMM2: out += w * (h * Wd); K-split x2, dbuf, swizzled ----------------
// round-1 exact.
#define G2_GRID 896    // 56 rt-slots * 8 nt * 2 khalf, multiple of 8
__global__ __launch_bounds__(256) void k_gemm2(
    const unsigned short* __restrict__ hbuf, const unsigned short* __restrict__ wdp,
    const int* __restrict__ cnt, const int* __restrict__ poffs,
    const int* __restrict__ tok, const float* __restrict__ wgt,
    float* __restrict__ out) {
  int lin = blockIdx.x;
  int s = (lin & 7) * (G2_GRID / 8) + (lin >> 3);   // bijective XCD chunk swizzle
  int rt = s >> 4;
  int r4 = s & 15;
  int nt = r4 >> 1, kh = r4 & 1;
  int rtTotal = poffs[NE_] >> 7;
  if (rt >= rtTotal) return;
  int ro = rt << 7;
  int e = 0;
#pragma unroll
  for (int i = 1; i < NE_; i++) if (poffs[i] <= ro) e = i;
  int po = poffs[e];
  int cnt_e = cnt[e];
  int mt = (ro - po) >> 7;

  __shared__ __align__(16) unsigned short As[2][4096];   // [q][m][8]
  __shared__ __align__(16) unsigned short BdS[2][4096];  // [h][q][nn][8]

  int tid = threadIdx.x;
  int lane = tid & 63, w = tid >> 6;
  int quad = lane >> 4, l15 = lane & 15;
  int wm = w >> 1, wn = w & 1;

  const unsigned short* abase = hbuf + (size_t)rt * 64 * 4096;
  const unsigned short* bb0 = wdp + (size_t)e * I_ * H_ + ((size_t)(2 * nt) * 64) * 2048;
  const unsigned short* bb1 = wdp + (size_t)e * I_ * H_ + ((size_t)(2 * nt + 1) * 64) * 2048;

  f32x4 zero = {0.f, 0.f, 0.f, 0.f};
  f32x4 acc[4][4];
#pragma unroll
  for (int mi = 0; mi < 4; mi++)
#pragma unroll
    for (int ni = 0; ni < 4; ni++) acc[mi][ni] = zero;

#define STAGE2(kt, b) do { \
    const unsigned short* asrc = abase + (size_t)(kt) * 4096 + w * 1024 + lane * 8; \
    gll16(asrc, &As[b][w * 1024]); \
    gll16(asrc + 512, &As[b][w * 1024 + 512]); \
    gll16(bb0 + (size_t)(kt) * 2048 + w * 512 + lane * 8, &BdS[b][w * 512]); \
    gll16(bb1 + (size_t)(kt) * 2048 + w * 512 + lane * 8, &BdS[b][2048 + w * 512]); \
  } while (0)

  int k0 = kh * 32;
  STAGE2(k0, 0);
  __syncthreads();
  for (int kk = 0; kk < 32; kk++) {
    int cur = kk & 1;
    if (kk < 31) STAGE2(k0 + kk + 1, cur ^ 1);
    bf16x8 af[4];
#pragma unroll
    for (int mi = 0; mi < 4; mi++)
      af[mi] = *(const bf16x8*)&As[cur][quad * 1024 + (wm * 64 + mi * 16 + l15) * 8];
#pragma unroll
    for (int ni = 0; ni < 4; ni++) {
      bf16x8 bd = *(const bf16x8*)&BdS[cur][wn * 2048 + quad * 512 + (ni * 16 + l15) * 8];
#pragma unroll
      for (int mi = 0; mi < 4; mi++)
        acc[mi][ni] = __builtin_amdgcn_mfma_f32_16x16x32_bf16(af[mi], bd, acc[mi][ni], 0, 0, 0);
    }
    __syncthreads();
  }
#undef STAGE2

  // epilogue: weighted fp32 atomic scatter (both k-halves accumulate)
  int rem = cnt_e - mt * 128;
#pragma unroll
  for (int mi = 0; mi < 4; mi++)
#pragma unroll
    for (int r = 0; r < 4; r++) {
      int row = wm * 64 + mi * 16 + quad * 4 + r;
      if (row < rem) {
        int g = po + mt * 128 + row;
        int tt = tok[g];
        float wt = wgt[g];
#pragma unroll
        for (int ni = 0; ni < 4; ni++) {
          int col = nt * 128 + wn * 64 + ni * 16 + l15;
          atomicAdd(&out[(size_t)tt * H_ + col], wt * acc[mi][ni][r]);
        }
      }
    }
}

extern "C" void kernel_launch(void* const* d_in, const int* in_sizes, int n_in,
                              void* d_out, int out_size, void* d_ws, size_t ws_size,
                              hipStream_t stream) {
  const float* x  = (const float*)d_in[0];
  const float* rw = (const float*)d_in[1];
  const float* eg = (const float*)d_in[2];
  const float* eu = (const float*)d_in[3];
  const float* ed = (const float*)d_in[4];
  const float* sg = (const float*)d_in[5];
  const float* su = (const float*)d_in[6];
  const float* sd = (const float*)d_in[7];
  float* out = (float*)d_out;
  char* ws = (char*)d_ws;

  int*   cnt  = (int*)(ws + 64);
  int*   poffs= (int*)(ws + 128);
  int*   topi = (int*)(ws + 4096);
  float* topw = (float*)(ws + 4096 + 16384);
  int*   tok  = (int*)(ws + 36864);
  float* wgt  = (float*)(ws + 66560);
  unsigned short* apack = (unsigned short*)(ws + 131072);                 // 14.68 MB
  unsigned short* hbuf  = (unsigned short*)(ws + 131072 + 14811136);      // 29.36 MB used max
  float* probs = (float*)(ws + 44302336);   // tail slack of hbuf region (64 KB)
  float* lse2  = (float*)(ws + 44367872);   // 8 KB
  unsigned short* wgp   = (unsigned short*)(ws + 131072 + 14811136 + 29491200);
  unsigned short* wup   = (unsigned short*)((char*)wgp + (size_t)NE_ * H_ * I_ * 2);
  unsigned short* wdp   = (unsigned short*)((char*)wup + (size_t)NE_ * H_ * I_ * 2);

  k_router<<<512, 256, 0, stream>>>(x, rw, topi, topw, probs, lse2, out);
  k_sched<<<1, 256, 0, stream>>>(probs, lse2, topi, topw, cnt, poffs,
                                 out + (size_t)T_ * H_, tok, wgt);
  k_prep<<<PREP_GRID, 256, 0, stream>>>(eg, eu, ed, sg, su, sd, wgp, wup, wdp,
                                        x, cnt, poffs, tok, apack);
  k_gemm1<<<G1_GRID, 256, 0, stream>>>(apack, wgp, wup, cnt, poffs, hbuf);
  k_gemm2<<<G2_GRID, 256, 0, stream>>>(hbuf, wdp, cnt, poffs, tok, wgt, out);
}